// Round 5
// baseline (394.337 us; speedup 1.0000x reference)
//
#include <hip/hip_runtime.h>

#define BB 4
#define TT 4096
#define CC 256

typedef __attribute__((ext_vector_type(8))) short short8;   // 8 x bf16 (4 VGPRs)
typedef __attribute__((ext_vector_type(4))) float f32x4;

#define SCALE 0.0625f  // C^-0.5 = 1/16
#define ECLAMP 60.0f   // exp-arg clamp, identical in zsum & attn

__device__ __forceinline__ float bf2f(unsigned short u) {
  union { unsigned int i; float f; } v; v.i = ((unsigned int)u) << 16; return v.f;
}
__device__ __forceinline__ unsigned short f2bf(float f) {
  union { float f; unsigned int i; } v; v.f = f;
  unsigned int x = v.i;
  unsigned int r = x + 0x7fffu + ((x >> 16) & 1u);  // RNE
  return (unsigned short)(r >> 16);
}
__device__ __forceinline__ unsigned int cvtpk(float a, float b) {  // bf16(a)|bf16(b)<<16
  unsigned int r; asm("v_cvt_pk_bf16_f32 %0, %1, %2" : "=v"(r) : "v"(a), "v"(b)); return r;
}

// ---------------- K0: input dtype detection ----------------
__global__ __launch_bounds__(256) void detect_kernel(const unsigned short* __restrict__ xu,
                                                     int* __restrict__ flag) {
  __shared__ int part[4];
  int tid = threadIdx.x;
  int cnt = 0;
#pragma unroll
  for (int i = 0; i < 32; i++) {
    unsigned short u = xu[tid * 32 + i];
    int e = (u >> 7) & 0xff;
    cnt += (e >= 0xC0) ? 1 : 0;
  }
#pragma unroll
  for (int off = 32; off >= 1; off >>= 1) cnt += __shfl_xor(cnt, off);
  if ((tid & 63) == 0) part[tid >> 6] = cnt;
  __syncthreads();
  if (tid == 0) flag[0] = (part[0] + part[1] + part[2] + part[3] > 64) ? 1 : 0;
}

// ---------------- K0b: ALL dtype conversions in ONE launch ----------------
__global__ __launch_bounds__(256) void cvt_all_kernel(
    const void* __restrict__ Wq, const void* __restrict__ Wk, const void* __restrict__ Wv,
    const void* __restrict__ bq, const void* __restrict__ bk, const void* __restrict__ bv,
    const void* __restrict__ gm, const void* __restrict__ bt,
    unsigned short* __restrict__ Wqb, unsigned short* __restrict__ Wkb,
    unsigned short* __restrict__ Wvb, unsigned short* __restrict__ bqb,
    unsigned short* __restrict__ bkb, unsigned short* __restrict__ bvb,
    unsigned short* __restrict__ gmb, unsigned short* __restrict__ btb,
    const int* __restrict__ flagp) {
  int bx = blockIdx.x, tid = threadIdx.x;
  const void* src;
  unsigned short* dst;
  int idx;
  if (bx < 256) { src = Wq; dst = Wqb; idx = bx * 256 + tid; }
  else if (bx < 512) { src = Wk; dst = Wkb; idx = (bx - 256) * 256 + tid; }
  else if (bx < 768) { src = Wv; dst = Wvb; idx = (bx - 512) * 256 + tid; }
  else {
    int w = bx - 768; idx = tid;
    src = (w == 0) ? bq : (w == 1) ? bk : (w == 2) ? bv : (w == 3) ? gm : bt;
    dst = (w == 0) ? bqb : (w == 1) ? bkb : (w == 2) ? bvb : (w == 3) ? gmb : btb;
  }
  dst[idx] = (*flagp) ? f2bf(((const float*)src)[idx]) : ((const unsigned short*)src)[idx];
}

// ---------------- K1: LayerNorm row stats (mu, rsqrt(var+eps)) ----------------
__global__ __launch_bounds__(256) void stats_kernel(const void* __restrict__ xv,
                                                    float2* __restrict__ stats,
                                                    const int* __restrict__ flagp) {
  int row = blockIdx.x * 4 + (threadIdx.x >> 6);
  int lane = threadIdx.x & 63;
  float f0, f1, f2, f3;
  if (*flagp) {
    const float* xr = (const float*)xv + (size_t)row * CC + lane * 4;
    float4 v = *(const float4*)xr;
    f0 = v.x; f1 = v.y; f2 = v.z; f3 = v.w;
  } else {
    const unsigned short* xr = (const unsigned short*)xv + (size_t)row * CC + lane * 4;
    uint2 v = *(const uint2*)xr;
    f0 = bf2f(v.x & 0xffffu); f1 = bf2f(v.x >> 16);
    f2 = bf2f(v.y & 0xffffu); f3 = bf2f(v.y >> 16);
  }
  float s = f0 + f1 + f2 + f3;
  float s2 = f0 * f0 + f1 * f1 + f2 * f2 + f3 * f3;
#pragma unroll
  for (int off = 32; off >= 1; off >>= 1) {
    s += __shfl_xor(s, off);
    s2 += __shfl_xor(s2, off);
  }
  if (lane == 0) {
    float mu = s * (1.0f / CC);
    float var = s2 * (1.0f / CC) - mu * mu;
    stats[row] = make_float2(mu, rsqrtf(var + 1e-5f));
  }
}

// ---------------- K2: fused LN + ALL THREE projections in one launch --------
__global__ __launch_bounds__(256) void qkv3_kernel(
    const void* __restrict__ xv, const float2* __restrict__ stats,
    const unsigned short* __restrict__ gmb, const unsigned short* __restrict__ btb,
    const unsigned short* __restrict__ Wq, const unsigned short* __restrict__ Wk,
    const unsigned short* __restrict__ Wv, const unsigned short* __restrict__ bq,
    const unsigned short* __restrict__ bk, const unsigned short* __restrict__ bv,
    unsigned short* __restrict__ oq, unsigned short* __restrict__ ok,
    unsigned short* __restrict__ ov, int row0, const int* __restrict__ flagp) {
  constexpr int LD = 56;
  alignas(16) __shared__ unsigned short As[128 * LD];
  alignas(16) __shared__ unsigned short Bs[128 * LD];
  __shared__ float gf[CC], bfv[CC];
  int tid = threadIdx.x;
  int flag = *flagp;
  gf[tid] = bf2f(gmb[tid]);
  bfv[tid] = bf2f(btb[tid]);
  int w = blockIdx.y >> 1;
  const unsigned short* Wb = (w == 0) ? Wq : (w == 1) ? Wk : Wv;
  const unsigned short* biasb = (w == 0) ? bq : (w == 1) ? bk : bv;
  unsigned short* outp = (w == 0) ? oq : (w == 1) ? ok : ov;
  int transposed = (w == 2);
  int row0e = row0 + blockIdx.z * TT;
  unsigned short* outpe = outp + (size_t)blockIdx.z * TT * CC;
  int m0 = blockIdx.x * 128, n0 = (blockIdx.y & 1) * 128;
  int wid = tid >> 6, lane = tid & 63, qd = lane >> 4, l15 = lane & 15;
  int wm = wid >> 1, wn = wid & 1;
  f32x4 acc[4][4] = {};
  int srow = tid >> 2, sc8 = (tid & 3) * 8;
  float2 st0 = stats[row0e + m0 + srow];
  float2 st1 = stats[row0e + m0 + srow + 64];
  for (int kk = 0; kk < 8; kk++) {
    int k0 = kk * 32;
    __syncthreads();
#pragma unroll
    for (int rr = 0; rr < 2; rr++) {
      int r = srow + rr * 64;
      float2 st = rr ? st1 : st0;
      float v[8];
      if (flag) {
        const float* xr = (const float*)xv + (size_t)(row0e + m0 + r) * CC + k0 + sc8;
        float4 a = *(const float4*)xr;
        float4 b2 = *(const float4*)(xr + 4);
        v[0] = a.x; v[1] = a.y; v[2] = a.z; v[3] = a.w;
        v[4] = b2.x; v[5] = b2.y; v[6] = b2.z; v[7] = b2.w;
      } else {
        uint4 u = *(const uint4*)((const unsigned short*)xv +
                                  (size_t)(row0e + m0 + r) * CC + k0 + sc8);
        v[0] = bf2f(u.x & 0xffffu); v[1] = bf2f(u.x >> 16);
        v[2] = bf2f(u.y & 0xffffu); v[3] = bf2f(u.y >> 16);
        v[4] = bf2f(u.z & 0xffffu); v[5] = bf2f(u.z >> 16);
        v[6] = bf2f(u.w & 0xffffu); v[7] = bf2f(u.w >> 16);
      }
      union { unsigned short s[8]; uint4 u; } o;
#pragma unroll
      for (int j = 0; j < 8; j++)
        o.s[j] = f2bf((v[j] - st.x) * st.y * gf[k0 + sc8 + j] + bfv[k0 + sc8 + j]);
      *(uint4*)&As[r * LD + sc8] = o.u;
    }
    *(uint4*)&Bs[srow * LD + sc8] =
        *(const uint4*)(Wb + (size_t)(n0 + srow) * CC + k0 + sc8);
    *(uint4*)&Bs[(srow + 64) * LD + sc8] =
        *(const uint4*)(Wb + (size_t)(n0 + srow + 64) * CC + k0 + sc8);
    __syncthreads();
    short8 a[4], bfr[4];
#pragma unroll
    for (int mi = 0; mi < 4; mi++)
      a[mi] = *(const short8*)&As[(wm * 64 + mi * 16 + l15) * LD + qd * 8];
#pragma unroll
    for (int ni = 0; ni < 4; ni++)
      bfr[ni] = *(const short8*)&Bs[(wn * 64 + ni * 16 + l15) * LD + qd * 8];
#pragma unroll
    for (int mi = 0; mi < 4; mi++)
#pragma unroll
      for (int ni = 0; ni < 4; ni++)
        acc[mi][ni] =
            __builtin_amdgcn_mfma_f32_16x16x32_bf16(a[mi], bfr[ni], acc[mi][ni], 0, 0, 0);
  }
#pragma unroll
  for (int mi = 0; mi < 4; mi++)
#pragma unroll
    for (int ni = 0; ni < 4; ni++) {
      int n = n0 + wn * 64 + ni * 16 + l15;
      float bsv = bf2f(biasb[n]);
#pragma unroll
      for (int r = 0; r < 4; r++) {
        int m = m0 + wm * 64 + mi * 16 + qd * 4 + r;
        unsigned short val = f2bf(acc[mi][ni][r] + bsv);
        if (transposed)
          outpe[(size_t)n * TT + m] = val;
        else
          outpe[(size_t)m * CC + n] = val;
      }
    }
}

// ---------------- K3n: zsumE — zsum + E^T bf16 store + fused V' = zinv*V ----
// E^T[s][t] = exp(min(S[t,s]*SCALE, ECLAMP)) stored bf16; Z[t] f32; V'[c][t]=zinv[t]*V.
__global__ __launch_bounds__(512, 2) void zsumE_kernel(
    const unsigned short* __restrict__ q, const unsigned short* __restrict__ k,
    const unsigned short* __restrict__ vt, float* __restrict__ zinvp,
    unsigned short* __restrict__ vpt, unsigned short* __restrict__ et) {
  __shared__ float Zp[8][64];
  __shared__ float zfin[64];
  int bx = blockIdx.x;
  int batch = (bx & 7) >> 1;
  int tile = (bx >> 3) * 2 + (bx & 1);  // [0,64)
  const unsigned short* qb = q + (size_t)batch * TT * CC;
  const unsigned short* kb = k + (size_t)batch * TT * CC;
  const unsigned short* vtb = vt + (size_t)batch * TT * CC;
  unsigned short* vptb = vpt + (size_t)batch * TT * CC;
  unsigned short* etb = et + (size_t)batch * TT * TT;  // E^T [s][t]
  float* zinv = zinvp + (size_t)batch * TT;
  int tid = threadIdx.x, wid = tid >> 6, lane = tid & 63, qd = lane >> 4, l15 = lane & 15;
  int t0 = tile * 64;
  short8 afix[4][8];  // Q[t-tile 64] fixed A operand
#pragma unroll
  for (int mi = 0; mi < 4; mi++)
#pragma unroll
    for (int kk = 0; kk < 8; kk++)
      afix[mi][kk] =
          *(const short8*)(qb + (size_t)(t0 + mi * 16 + l15) * CC + kk * 32 + qd * 8);
  float zacc[4][4] = {};
  const unsigned short* kbase = kb + (size_t)(wid * 16 + l15) * CC + qd * 8;
  unsigned short* ebase = etb + (size_t)(wid * 16 + l15) * TT + t0 + qd * 4;
  short8 kpre[8];
#pragma unroll
  for (int kk = 0; kk < 8; kk++) kpre[kk] = *(const short8*)(kbase + kk * 32);
  for (int sc = 0; sc < TT; sc += 128) {
    f32x4 sacc[4] = {};
    __builtin_amdgcn_s_setprio(1);
#pragma unroll
    for (int kk = 0; kk < 8; kk++) {
      short8 b0 = kpre[kk];
#pragma unroll
      for (int mi = 0; mi < 4; mi++)
        sacc[mi] = __builtin_amdgcn_mfma_f32_16x16x32_bf16(afix[mi][kk], b0, sacc[mi], 0, 0, 0);
    }
    __builtin_amdgcn_s_setprio(0);
    int scn = (sc + 128 < TT) ? sc + 128 : 0;
#pragma unroll
    for (int kk = 0; kk < 8; kk++)
      kpre[kk] = *(const short8*)(kbase + (size_t)scn * CC + kk * 32);
    unsigned short* eb = ebase + (size_t)sc * TT;
#pragma unroll
    for (int mi = 0; mi < 4; mi++) {
      float e0 = __expf(fminf(sacc[mi][0] * SCALE, ECLAMP));
      float e1 = __expf(fminf(sacc[mi][1] * SCALE, ECLAMP));
      float e2 = __expf(fminf(sacc[mi][2] * SCALE, ECLAMP));
      float e3 = __expf(fminf(sacc[mi][3] * SCALE, ECLAMP));
      zacc[mi][0] += e0; zacc[mi][1] += e1; zacc[mi][2] += e2; zacc[mi][3] += e3;
      uint2 pk;
      pk.x = cvtpk(e0, e1);
      pk.y = cvtpk(e2, e3);
      *(uint2*)(eb + mi * 16) = pk;  // row s, cols t0+mi*16+qd*4 .. +4
    }
  }
#pragma unroll
  for (int mi = 0; mi < 4; mi++)
#pragma unroll
    for (int r = 0; r < 4; r++) {
      float z = zacc[mi][r];
      z += __shfl_xor(z, 1); z += __shfl_xor(z, 2);
      z += __shfl_xor(z, 4); z += __shfl_xor(z, 8);
      zacc[mi][r] = z;
    }
  if (l15 == 0) {
#pragma unroll
    for (int mi = 0; mi < 4; mi++)
#pragma unroll
      for (int r = 0; r < 4; r++) Zp[wid][mi * 16 + qd * 4 + r] = zacc[mi][r];
  }
  __syncthreads();
  if (tid < 64) {
    float Z = 0.0f;
#pragma unroll
    for (int w = 0; w < 8; w++) Z += Zp[w][tid];
    float zi = 1.0f / Z;
    zinv[t0 + tid] = zi;
    zfin[tid] = zi;
  }
  __syncthreads();
  // ---- fused V' epilogue: V'[c][t0..t0+64] = zinv[t] * V[c][t] ----
  {
    int c = tid >> 1, half = tid & 1;
    const unsigned short* vsrc = vtb + (size_t)c * TT + t0 + half * 32;
    unsigned short* vdst = vptb + (size_t)c * TT + t0 + half * 32;
#pragma unroll
    for (int j = 0; j < 4; j++) {
      short8 v = *(const short8*)(vsrc + j * 8);
      float f[8];
#pragma unroll
      for (int e = 0; e < 8; e++)
        f[e] = bf2f((unsigned short)v[e]) * zfin[half * 32 + j * 8 + e];
      union { unsigned int u[4]; short8 s; } o;
      o.u[0] = cvtpk(f[0], f[1]);
      o.u[1] = cvtpk(f[2], f[3]);
      o.u[2] = cvtpk(f[4], f[5]);
      o.u[3] = cvtpk(f[6], f[7]);
      *(short8*)(vdst + j * 8) = o.s;
    }
  }
}

// ---------------- K4n: attnG — barrier-free streaming GEMM out = E^T V' + x -
__global__ __launch_bounds__(512, 2) void attnG_kernel(
    const unsigned short* __restrict__ et, const unsigned short* __restrict__ vpt,
    const void* __restrict__ xv, float* __restrict__ out,
    const int* __restrict__ flagp) {
  int bx = blockIdx.x;
  int batch = (bx & 7) >> 1;
  int tile = (bx >> 3) * 2 + (bx & 1);  // [0,64)
  int flag = *flagp;
  const unsigned short* etb = et + (size_t)batch * TT * TT;
  const unsigned short* vptb = vpt + (size_t)batch * TT * CC;
  int row0e = batch * TT;
  int tid = threadIdx.x, wid = tid >> 6, lane = tid & 63, qd = lane >> 4, l15 = lane & 15;
  int s0 = tile * 64;
  f32x4 oacc[4][2] = {};
  const unsigned short* arow[4];
#pragma unroll
  for (int mi = 0; mi < 4; mi++)
    arow[mi] = etb + (size_t)(s0 + mi * 16 + l15) * TT + qd * 8;
  const unsigned short* vrow[2];
#pragma unroll
  for (int ni = 0; ni < 2; ni++)
    vrow[ni] = vptb + (size_t)(wid * 32 + ni * 16 + l15) * TT + qd * 8;
  short8 apre[16], vpre[8];
#pragma unroll
  for (int kt = 0; kt < 4; kt++) {
#pragma unroll
    for (int mi = 0; mi < 4; mi++)
      apre[kt * 4 + mi] = *(const short8*)(arow[mi] + kt * 32);
#pragma unroll
    for (int ni = 0; ni < 2; ni++)
      vpre[kt * 2 + ni] = *(const short8*)(vrow[ni] + kt * 32);
  }
  for (int tc = 0; tc < TT; tc += 128) {
    int tn = (tc + 128 < TT) ? tc + 128 : 0;
    __builtin_amdgcn_s_setprio(1);
#pragma unroll
    for (int kt = 0; kt < 4; kt++) {
#pragma unroll
      for (int ni = 0; ni < 2; ni++) {
        short8 b = vpre[kt * 2 + ni];
#pragma unroll
        for (int mi = 0; mi < 4; mi++)
          oacc[mi][ni] = __builtin_amdgcn_mfma_f32_16x16x32_bf16(apre[kt * 4 + mi], b,
                                                                 oacc[mi][ni], 0, 0, 0);
      }
    }
    __builtin_amdgcn_s_setprio(0);
    // prefetch next t-slab (latency hides under next MFMA burst + wave drift)
#pragma unroll
    for (int kt = 0; kt < 4; kt++) {
#pragma unroll
      for (int mi = 0; mi < 4; mi++)
        apre[kt * 4 + mi] = *(const short8*)(arow[mi] + tn + kt * 32);
#pragma unroll
      for (int ni = 0; ni < 2; ni++)
        vpre[kt * 2 + ni] = *(const short8*)(vrow[ni] + tn + kt * 32);
    }
  }
  // epilogue: out(f32) = oacc + x
#pragma unroll
  for (int mi = 0; mi < 4; mi++)
#pragma unroll
    for (int ni = 0; ni < 2; ni++)
#pragma unroll
      for (int r = 0; r < 4; r++) {
        int s = s0 + mi * 16 + qd * 4 + r;
        int c = wid * 32 + ni * 16 + l15;
        size_t idx = ((size_t)(row0e + s)) * CC + c;
        float xr = flag ? ((const float*)xv)[idx] : bf2f(((const unsigned short*)xv)[idx]);
        out[idx] = oacc[mi][ni][r] + xr;
      }
}

// ---------------- K3: zsum v8 (fallback) ------------------------------------
__global__ __launch_bounds__(512, 2) void zsum_kernel(
    const unsigned short* __restrict__ q, const unsigned short* __restrict__ k,
    float* __restrict__ zinvp, int swiz) {
  __shared__ float Zp[8][64];
  int bx = blockIdx.x;
  int batch = swiz ? ((bx & 7) >> 1) : 0;
  int tile = swiz ? ((bx >> 3) * 2 + (bx & 1)) : bx;
  const unsigned short* qb = q + (size_t)batch * TT * CC;
  const unsigned short* kb = k + (size_t)batch * TT * CC;
  float* zinv = zinvp + (size_t)batch * TT;
  int tid = threadIdx.x, wid = tid >> 6, lane = tid & 63, qd = lane >> 4, l15 = lane & 15;
  int t0 = tile * 64;
  short8 afix[4][8];
#pragma unroll
  for (int mi = 0; mi < 4; mi++)
#pragma unroll
    for (int kk = 0; kk < 8; kk++)
      afix[mi][kk] =
          *(const short8*)(qb + (size_t)(t0 + mi * 16 + l15) * CC + kk * 32 + qd * 8);
  float zacc[4][4] = {};
  const unsigned short* kbase = kb + (size_t)(wid * 16 + l15) * CC + qd * 8;
  short8 kpre[8];
#pragma unroll
  for (int kk = 0; kk < 8; kk++) kpre[kk] = *(const short8*)(kbase + kk * 32);
  for (int sc = 0; sc < TT; sc += 128) {
    f32x4 sacc[4] = {};
    __builtin_amdgcn_s_setprio(1);
#pragma unroll
    for (int kk = 0; kk < 8; kk++) {
      short8 b0 = kpre[kk];
#pragma unroll
      for (int mi = 0; mi < 4; mi++)
        sacc[mi] = __builtin_amdgcn_mfma_f32_16x16x32_bf16(afix[mi][kk], b0, sacc[mi], 0, 0, 0);
    }
    __builtin_amdgcn_s_setprio(0);
    int scn = (sc + 128 < TT) ? sc + 128 : 0;
#pragma unroll
    for (int kk = 0; kk < 8; kk++)
      kpre[kk] = *(const short8*)(kbase + (size_t)scn * CC + kk * 32);
#pragma unroll
    for (int mi = 0; mi < 4; mi++)
#pragma unroll
      for (int r = 0; r < 4; r++)
        zacc[mi][r] += __expf(fminf(sacc[mi][r] * SCALE, ECLAMP));
  }
#pragma unroll
  for (int mi = 0; mi < 4; mi++)
#pragma unroll
    for (int r = 0; r < 4; r++) {
      float z = zacc[mi][r];
      z += __shfl_xor(z, 1); z += __shfl_xor(z, 2);
      z += __shfl_xor(z, 4); z += __shfl_xor(z, 8);
      zacc[mi][r] = z;
    }
  if (l15 == 0) {
#pragma unroll
    for (int mi = 0; mi < 4; mi++)
#pragma unroll
      for (int r = 0; r < 4; r++) Zp[wid][mi * 16 + qd * 4 + r] = zacc[mi][r];
  }
  __syncthreads();
  if (tid < 64) {
    float Z = 0.0f;
#pragma unroll
    for (int w = 0; w < 8; w++) Z += Zp[w][tid];
    zinv[t0 + tid] = 1.0f / Z;
  }
}

// ---------------- K4: attn v10 (fallback) -----------------------------------
__global__ __launch_bounds__(512, 2) void attn_kernel(
    const unsigned short* __restrict__ q, const unsigned short* __restrict__ k,
    const unsigned short* __restrict__ vt, const float* __restrict__ zinvp,
    const void* __restrict__ xv, float* __restrict__ out, int swiz, int row0,
    const int* __restrict__ flagp) {
  constexpr int LPt = 136;
  alignas(16) __shared__ unsigned short Pt[2][64 * LPt];
  int bx = blockIdx.x;
  int batch = swiz ? ((bx & 7) >> 1) : 0;
  int tile = swiz ? ((bx >> 3) * 2 + (bx & 1)) : bx;
  int flag = *flagp;
  const unsigned short* qb = q + (size_t)batch * TT * CC;
  const unsigned short* kb = k + (size_t)batch * TT * CC;
  const unsigned short* vtb = vt + (size_t)batch * TT * CC;
  const float* zinv = zinvp + (size_t)batch * TT;
  int row0e = swiz ? batch * TT : row0;
  int tid = threadIdx.x, wid = tid >> 6, lane = tid & 63, qd = lane >> 4, l15 = lane & 15;
  int s0 = tile * 64;
  short8 afix[4][8];
#pragma unroll
  for (int mi = 0; mi < 4; mi++)
#pragma unroll
    for (int kk = 0; kk < 8; kk++)
      afix[mi][kk] =
          *(const short8*)(kb + (size_t)(s0 + mi * 16 + l15) * CC + kk * 32 + qd * 8);
  f32x4 oacc[4][2] = {};
  const unsigned short* qrow = qb + (size_t)(wid * 16 + l15) * CC + qd * 8;
  const unsigned short* vrow[2];
#pragma unroll
  for (int ni = 0; ni < 2; ni++)
    vrow[ni] = vtb + (size_t)(wid * 32 + ni * 16 + l15) * TT + qd * 8;
  short8 qpre[8], vpre[8];
#pragma unroll
  for (int kk = 0; kk < 8; kk++) qpre[kk] = *(const short8*)(qrow + kk * 32);
#pragma unroll
  for (int kt = 0; kt < 4; kt++)
#pragma unroll
    for (int ni = 0; ni < 2; ni++)
      vpre[kt * 2 + ni] = *(const short8*)(vrow[ni] + kt * 32);
  int t_loc = wid * 16 + l15;
  float zpre = zinv[t_loc];
  {
    f32x4 sacc[4] = {};
    __builtin_amdgcn_s_setprio(1);
#pragma unroll
    for (int kk = 0; kk < 8; kk++) {
      short8 b0 = qpre[kk];
#pragma unroll
      for (int mi = 0; mi < 4; mi++)
        sacc[mi] = __builtin_amdgcn_mfma_f32_16x16x32_bf16(afix[mi][kk], b0, sacc[mi], 0, 0, 0);
    }
    __builtin_amdgcn_s_setprio(0);
#pragma unroll
    for (int kk = 0; kk < 8; kk++)
      qpre[kk] = *(const short8*)(qrow + (size_t)128 * CC + kk * 32);
    float zz = zpre;
    zpre = zinv[128 + t_loc];
#pragma unroll
    for (int mi = 0; mi < 4; mi++)
#pragma unroll
      for (int r = 0; r < 4; r++) {
        float p = __expf(fminf(sacc[mi][r] * SCALE, ECLAMP)) * zz;
        Pt[0][(mi * 16 + qd * 4 + r) * LPt + t_loc] = f2bf(p);
      }
  }
  __syncthreads();
  for (int it = 1; it < 32; it++) {
    int tc = it * 128;
    int tn = (tc + 128 < TT) ? tc + 128 : 0;
    int buf = it & 1;
    f32x4 sacc[4] = {};
    __builtin_amdgcn_s_setprio(1);
#pragma unroll
    for (int kk = 0; kk < 8; kk++) {
      short8 b0 = qpre[kk];
#pragma unroll
      for (int mi = 0; mi < 4; mi++)
        sacc[mi] = __builtin_amdgcn_mfma_f32_16x16x32_bf16(afix[mi][kk], b0, sacc[mi], 0, 0, 0);
    }
    __builtin_amdgcn_s_setprio(0);
#pragma unroll
    for (int kk = 0; kk < 8; kk++)
      qpre[kk] = *(const short8*)(qrow + (size_t)tn * CC + kk * 32);
    float zz = zpre;
    zpre = zinv[tn + t_loc];
#pragma unroll
    for (int mi = 0; mi < 4; mi++)
#pragma unroll
      for (int r = 0; r < 4; r++) {
        float p = __expf(fminf(sacc[mi][r] * SCALE, ECLAMP)) * zz;
        Pt[buf][(mi * 16 + qd * 4 + r) * LPt + t_loc] = f2bf(p);
      }
    __builtin_amdgcn_s_setprio(1);
#pragma unroll
    for (int kt = 0; kt < 4; kt++) {
      short8 a[4];
#pragma unroll
      for (int mi = 0; mi < 4; mi++)
        a[mi] = *(const short8*)&Pt[buf ^ 1][(mi * 16 + l15) * LPt + kt * 32 + qd * 8];
#pragma unroll
      for (int ni = 0; ni < 2; ni++) {
        short8 b = vpre[kt * 2 + ni];
#pragma unroll
        for (int mi = 0; mi < 4; mi++)
          oacc[mi][ni] =
              __builtin_amdgcn_mfma_f32_16x16x32_bf16(a[mi], b, oacc[mi][ni], 0, 0, 0);
      }
    }
    __builtin_amdgcn_s_setprio(0);
#pragma unroll
    for (int kt = 0; kt < 4; kt++)
#pragma unroll
      for (int ni = 0; ni < 2; ni++)
        vpre[kt * 2 + ni] = *(const short8*)(vrow[ni] + tc + kt * 32);
    __syncthreads();
  }
  __builtin_amdgcn_s_setprio(1);
#pragma unroll
  for (int kt = 0; kt < 4; kt++) {
    short8 a[4];
#pragma unroll
    for (int mi = 0; mi < 4; mi++)
      a[mi] = *(const short8*)&Pt[1][(mi * 16 + l15) * LPt + kt * 32 + qd * 8];
#pragma unroll
    for (int ni = 0; ni < 2; ni++) {
      short8 b = vpre[kt * 2 + ni];
#pragma unroll
      for (int mi = 0; mi < 4; mi++)
        oacc[mi][ni] =
            __builtin_amdgcn_mfma_f32_16x16x32_bf16(a[mi], b, oacc[mi][ni], 0, 0, 0);
    }
  }
  __builtin_amdgcn_s_setprio(0);
#pragma unroll
  for (int mi = 0; mi < 4; mi++)
#pragma unroll
    for (int ni = 0; ni < 2; ni++)
#pragma unroll
      for (int r = 0; r < 4; r++) {
        int s = s0 + mi * 16 + qd * 4 + r;
        int c = wid * 32 + ni * 16 + l15;
        size_t idx = ((size_t)(row0e + s)) * CC + c;
        float xr = flag ? ((const float*)xv)[idx] : bf2f(((const unsigned short*)xv)[idx]);
        out[idx] = oacc[mi][ni][r] + xr;
      }
}

extern "C" void kernel_launch(void* const* d_in, const int* in_sizes, int n_in,
                              void* d_out, int out_size, void* d_ws, size_t ws_size,
                              hipStream_t stream) {
  const void* x = d_in[0];
  const void* gamma = d_in[1];
  const void* beta = d_in[2];
  const void* Wq = d_in[3];
  const void* bq = d_in[4];
  const void* Wk = d_in[5];
  const void* bk = d_in[6];
  const void* Wv = d_in[7];
  const void* bv = d_in[8];
  float* out = (float*)d_out;  // reference output dtype: float32

  char* ws = (char*)d_ws;
  int* flag = (int*)(ws + 0);
  float2* stats = (float2*)(ws + 1024);                      // 128 KiB
  unsigned short* gmb = (unsigned short*)(ws + 132096);
  unsigned short* btb = (unsigned short*)(ws + 132608);
  unsigned short* bqb = (unsigned short*)(ws + 133120);
  unsigned short* bkb = (unsigned short*)(ws + 133632);
  unsigned short* bvb = (unsigned short*)(ws + 134144);
  unsigned short* Wqb = (unsigned short*)(ws + 135168);      // 128 KiB each
  unsigned short* Wkb = (unsigned short*)(ws + 266240);
  unsigned short* Wvb = (unsigned short*)(ws + 397312);
  float* zinv = (float*)(ws + 593920);                       // 64 KiB
  unsigned short* qb = (unsigned short*)(ws + 1048576);
  const int newfull = (ws_size >= 168820736u);               // + V'(8M) + E^T(128M)
  const int full = (ws_size >= 26214400u);
  size_t qkv_bytes = full ? 8388608u : 2097152u;
  unsigned short* kb = (unsigned short*)((char*)qb + qkv_bytes);
  unsigned short* vtb = (unsigned short*)((char*)kb + qkv_bytes);  // V^T [b][c][t]
  unsigned short* vpt = (unsigned short*)(ws + 26214400);          // V'^T, 8 MiB
  unsigned short* et = (unsigned short*)(ws + 34603008);           // E^T, 128 MiB

  detect_kernel<<<dim3(1), dim3(256), 0, stream>>>((const unsigned short*)x, flag);
  cvt_all_kernel<<<dim3(773), dim3(256), 0, stream>>>(Wq, Wk, Wv, bq, bk, bv, gamma, beta,
                                                      Wqb, Wkb, Wvb, bqb, bkb, bvb, gmb,
                                                      btb, flag);
  stats_kernel<<<dim3(BB * TT / 4), dim3(256), 0, stream>>>(x, stats, flag);

  if (newfull) {
    qkv3_kernel<<<dim3(32, 6, BB), dim3(256), 0, stream>>>(
        x, stats, gmb, btb, Wqb, Wkb, Wvb, bqb, bkb, bvb, qb, kb, vtb, 0, flag);
    zsumE_kernel<<<dim3(256), dim3(512), 0, stream>>>(qb, kb, vtb, zinv, vpt, et);
    attnG_kernel<<<dim3(256), dim3(512), 0, stream>>>(et, vpt, x, out, flag);
  } else if (full) {
    qkv3_kernel<<<dim3(32, 6, BB), dim3(256), 0, stream>>>(
        x, stats, gmb, btb, Wqb, Wkb, Wvb, bqb, bkb, bvb, qb, kb, vtb, 0, flag);
    zsum_kernel<<<dim3(256), dim3(512), 0, stream>>>(qb, kb, zinv, 1);
    attn_kernel<<<dim3(256), dim3(512), 0, stream>>>(qb, kb, vtb, zinv, x, out, 1, 0,
                                                     flag);
  } else {
    for (int b = 0; b < BB; b++) {
      int row0 = b * TT;
      qkv3_kernel<<<dim3(32, 6, 1), dim3(256), 0, stream>>>(
          x, stats, gmb, btb, Wqb, Wkb, Wvb, bqb, bkb, bvb, qb, kb, vtb, row0, flag);
      zsum_kernel<<<dim3(64), dim3(512), 0, stream>>>(qb, kb, zinv, 0);
      attn_kernel<<<dim3(64), dim3(512), 0, stream>>>(qb, kb, vtb, zinv, x, out, 0, row0,
                                                      flag);
    }
  }
}

// Round 6
// 256.370 us; speedup vs baseline: 1.5382x; 1.5382x over previous
//
#include <hip/hip_runtime.h>

#define BB 4
#define TT 4096
#define CC 256

typedef __attribute__((ext_vector_type(8))) short short8;   // 8 x bf16 (4 VGPRs)
typedef __attribute__((ext_vector_type(4))) float f32x4;

#define SCALE 0.0625f  // C^-0.5 = 1/16
#define ECLAMP 60.0f   // exp-arg clamp

__device__ __forceinline__ float bf2f(unsigned short u) {
  union { unsigned int i; float f; } v; v.i = ((unsigned int)u) << 16; return v.f;
}
__device__ __forceinline__ unsigned short f2bf(float f) {
  union { float f; unsigned int i; } v; v.f = f;
  unsigned int x = v.i;
  unsigned int r = x + 0x7fffu + ((x >> 16) & 1u);  // RNE
  return (unsigned short)(r >> 16);
}
__device__ __forceinline__ unsigned int cvtpk(float a, float b) {  // bf16(a)|bf16(b)<<16
  unsigned int r; asm("v_cvt_pk_bf16_f32 %0, %1, %2" : "=v"(r) : "v"(a), "v"(b)); return r;
}

// ---------------- K0: input dtype detection ----------------
__global__ __launch_bounds__(256) void detect_kernel(const unsigned short* __restrict__ xu,
                                                     int* __restrict__ flag) {
  __shared__ int part[4];
  int tid = threadIdx.x;
  int cnt = 0;
#pragma unroll
  for (int i = 0; i < 32; i++) {
    unsigned short u = xu[tid * 32 + i];
    int e = (u >> 7) & 0xff;
    cnt += (e >= 0xC0) ? 1 : 0;
  }
#pragma unroll
  for (int off = 32; off >= 1; off >>= 1) cnt += __shfl_xor(cnt, off);
  if ((tid & 63) == 0) part[tid >> 6] = cnt;
  __syncthreads();
  if (tid == 0) flag[0] = (part[0] + part[1] + part[2] + part[3] > 64) ? 1 : 0;
}

// ---------------- K0b: ALL dtype conversions in ONE launch ----------------
__global__ __launch_bounds__(256) void cvt_all_kernel(
    const void* __restrict__ Wq, const void* __restrict__ Wk, const void* __restrict__ Wv,
    const void* __restrict__ bq, const void* __restrict__ bk, const void* __restrict__ bv,
    const void* __restrict__ gm, const void* __restrict__ bt,
    unsigned short* __restrict__ Wqb, unsigned short* __restrict__ Wkb,
    unsigned short* __restrict__ Wvb, unsigned short* __restrict__ bqb,
    unsigned short* __restrict__ bkb, unsigned short* __restrict__ bvb,
    unsigned short* __restrict__ gmb, unsigned short* __restrict__ btb,
    const int* __restrict__ flagp) {
  int bx = blockIdx.x, tid = threadIdx.x;
  const void* src;
  unsigned short* dst;
  int idx;
  if (bx < 256) { src = Wq; dst = Wqb; idx = bx * 256 + tid; }
  else if (bx < 512) { src = Wk; dst = Wkb; idx = (bx - 256) * 256 + tid; }
  else if (bx < 768) { src = Wv; dst = Wvb; idx = (bx - 512) * 256 + tid; }
  else {
    int w = bx - 768; idx = tid;
    src = (w == 0) ? bq : (w == 1) ? bk : (w == 2) ? bv : (w == 3) ? gm : bt;
    dst = (w == 0) ? bqb : (w == 1) ? bkb : (w == 2) ? bvb : (w == 3) ? gmb : btb;
  }
  dst[idx] = (*flagp) ? f2bf(((const float*)src)[idx]) : ((const unsigned short*)src)[idx];
}

// ---------------- K1: LayerNorm row stats (mu, rsqrt(var+eps)) ----------------
__global__ __launch_bounds__(256) void stats_kernel(const void* __restrict__ xv,
                                                    float2* __restrict__ stats,
                                                    const int* __restrict__ flagp) {
  int row = blockIdx.x * 4 + (threadIdx.x >> 6);
  int lane = threadIdx.x & 63;
  float f0, f1, f2, f3;
  if (*flagp) {
    const float* xr = (const float*)xv + (size_t)row * CC + lane * 4;
    float4 v = *(const float4*)xr;
    f0 = v.x; f1 = v.y; f2 = v.z; f3 = v.w;
  } else {
    const unsigned short* xr = (const unsigned short*)xv + (size_t)row * CC + lane * 4;
    uint2 v = *(const uint2*)xr;
    f0 = bf2f(v.x & 0xffffu); f1 = bf2f(v.x >> 16);
    f2 = bf2f(v.y & 0xffffu); f3 = bf2f(v.y >> 16);
  }
  float s = f0 + f1 + f2 + f3;
  float s2 = f0 * f0 + f1 * f1 + f2 * f2 + f3 * f3;
#pragma unroll
  for (int off = 32; off >= 1; off >>= 1) {
    s += __shfl_xor(s, off);
    s2 += __shfl_xor(s2, off);
  }
  if (lane == 0) {
    float mu = s * (1.0f / CC);
    float var = s2 * (1.0f / CC) - mu * mu;
    stats[row] = make_float2(mu, rsqrtf(var + 1e-5f));
  }
}

// ---------------- K2: fused LN + ALL THREE projections in one launch --------
__global__ __launch_bounds__(256) void qkv3_kernel(
    const void* __restrict__ xv, const float2* __restrict__ stats,
    const unsigned short* __restrict__ gmb, const unsigned short* __restrict__ btb,
    const unsigned short* __restrict__ Wq, const unsigned short* __restrict__ Wk,
    const unsigned short* __restrict__ Wv, const unsigned short* __restrict__ bq,
    const unsigned short* __restrict__ bk, const unsigned short* __restrict__ bv,
    unsigned short* __restrict__ oq, unsigned short* __restrict__ ok,
    unsigned short* __restrict__ ov, int row0, const int* __restrict__ flagp) {
  constexpr int LD = 56;
  alignas(16) __shared__ unsigned short As[128 * LD];
  alignas(16) __shared__ unsigned short Bs[128 * LD];
  __shared__ float gf[CC], bfv[CC];
  int tid = threadIdx.x;
  int flag = *flagp;
  gf[tid] = bf2f(gmb[tid]);
  bfv[tid] = bf2f(btb[tid]);
  int w = blockIdx.y >> 1;
  const unsigned short* Wb = (w == 0) ? Wq : (w == 1) ? Wk : Wv;
  const unsigned short* biasb = (w == 0) ? bq : (w == 1) ? bk : bv;
  unsigned short* outp = (w == 0) ? oq : (w == 1) ? ok : ov;
  int transposed = (w == 2);
  int row0e = row0 + blockIdx.z * TT;
  unsigned short* outpe = outp + (size_t)blockIdx.z * TT * CC;
  int m0 = blockIdx.x * 128, n0 = (blockIdx.y & 1) * 128;
  int wid = tid >> 6, lane = tid & 63, qd = lane >> 4, l15 = lane & 15;
  int wm = wid >> 1, wn = wid & 1;
  f32x4 acc[4][4] = {};
  int srow = tid >> 2, sc8 = (tid & 3) * 8;
  float2 st0 = stats[row0e + m0 + srow];
  float2 st1 = stats[row0e + m0 + srow + 64];
  for (int kk = 0; kk < 8; kk++) {
    int k0 = kk * 32;
    __syncthreads();
#pragma unroll
    for (int rr = 0; rr < 2; rr++) {
      int r = srow + rr * 64;
      float2 st = rr ? st1 : st0;
      float v[8];
      if (flag) {
        const float* xr = (const float*)xv + (size_t)(row0e + m0 + r) * CC + k0 + sc8;
        float4 a = *(const float4*)xr;
        float4 b2 = *(const float4*)(xr + 4);
        v[0] = a.x; v[1] = a.y; v[2] = a.z; v[3] = a.w;
        v[4] = b2.x; v[5] = b2.y; v[6] = b2.z; v[7] = b2.w;
      } else {
        uint4 u = *(const uint4*)((const unsigned short*)xv +
                                  (size_t)(row0e + m0 + r) * CC + k0 + sc8);
        v[0] = bf2f(u.x & 0xffffu); v[1] = bf2f(u.x >> 16);
        v[2] = bf2f(u.y & 0xffffu); v[3] = bf2f(u.y >> 16);
        v[4] = bf2f(u.z & 0xffffu); v[5] = bf2f(u.z >> 16);
        v[6] = bf2f(u.w & 0xffffu); v[7] = bf2f(u.w >> 16);
      }
      union { unsigned short s[8]; uint4 u; } o;
#pragma unroll
      for (int j = 0; j < 8; j++)
        o.s[j] = f2bf((v[j] - st.x) * st.y * gf[k0 + sc8 + j] + bfv[k0 + sc8 + j]);
      *(uint4*)&As[r * LD + sc8] = o.u;
    }
    *(uint4*)&Bs[srow * LD + sc8] =
        *(const uint4*)(Wb + (size_t)(n0 + srow) * CC + k0 + sc8);
    *(uint4*)&Bs[(srow + 64) * LD + sc8] =
        *(const uint4*)(Wb + (size_t)(n0 + srow + 64) * CC + k0 + sc8);
    __syncthreads();
    short8 a[4], bfr[4];
#pragma unroll
    for (int mi = 0; mi < 4; mi++)
      a[mi] = *(const short8*)&As[(wm * 64 + mi * 16 + l15) * LD + qd * 8];
#pragma unroll
    for (int ni = 0; ni < 4; ni++)
      bfr[ni] = *(const short8*)&Bs[(wn * 64 + ni * 16 + l15) * LD + qd * 8];
#pragma unroll
    for (int mi = 0; mi < 4; mi++)
#pragma unroll
      for (int ni = 0; ni < 4; ni++)
        acc[mi][ni] =
            __builtin_amdgcn_mfma_f32_16x16x32_bf16(a[mi], bfr[ni], acc[mi][ni], 0, 0, 0);
  }
#pragma unroll
  for (int mi = 0; mi < 4; mi++)
#pragma unroll
    for (int ni = 0; ni < 4; ni++) {
      int n = n0 + wn * 64 + ni * 16 + l15;
      float bsv = bf2f(biasb[n]);
#pragma unroll
      for (int r = 0; r < 4; r++) {
        int m = m0 + wm * 64 + mi * 16 + qd * 4 + r;
        unsigned short val = f2bf(acc[mi][ni][r] + bsv);
        if (transposed)
          outpe[(size_t)n * TT + m] = val;
        else
          outpe[(size_t)m * CC + n] = val;
      }
    }
}

// ---------------- K3n: zsumE v2 — fragment-layout E + V' stores -------------
// E fragment layout (shorts): [batch:16M][s_tile64:262144][kt32:2048][mi:512][lane*8+e]
// V' fragment layout (shorts): [batch:1M][c16:65536? -> (c16*128+t32)*512][lane*8+e]
__global__ __launch_bounds__(512, 2) void zsumE_kernel(
    const unsigned short* __restrict__ q, const unsigned short* __restrict__ k,
    const unsigned short* __restrict__ vt, float* __restrict__ zinvp,
    unsigned short* __restrict__ vpt, unsigned short* __restrict__ et) {
  __shared__ float Zp[8][64];
  __shared__ float zfin[64];
  int bx = blockIdx.x;
  int batch = (bx & 7) >> 1;
  int tile = (bx >> 3) * 2 + (bx & 1);  // t-tile [0,64)
  const unsigned short* qb = q + (size_t)batch * TT * CC;
  const unsigned short* kb = k + (size_t)batch * TT * CC;
  const unsigned short* vtb = vt + (size_t)batch * TT * CC;
  float* zinv = zinvp + (size_t)batch * TT;
  int tid = threadIdx.x, wid = tid >> 6, lane = tid & 63, qd = lane >> 4, l15 = lane & 15;
  int t0 = tile * 64;
  short8 afix[4][8];  // Q[t-tile 64] fixed A operand (AGPR-parked)
#pragma unroll
  for (int mi = 0; mi < 4; mi++)
#pragma unroll
    for (int kk = 0; kk < 8; kk++)
      afix[mi][kk] =
          *(const short8*)(qb + (size_t)(t0 + mi * 16 + l15) * CC + kk * 32 + qd * 8);
  float zacc[4][4] = {};
  const unsigned short* kbase = kb + (size_t)(wid * 16 + l15) * CC + qd * 8;
  // fragment store base: s_tile = (sc>>6)+(wid>>2); kt32 = tile*2+(mi>>1); mi_c = wid&3
  int lanebase_e = ((qd >> 1) * 16 + l15) * 8 + (qd & 1) * 4;  // shorts
  unsigned short* ebase0 = et + (size_t)batch * 16777216u + (size_t)(tile * 2) * 2048 +
                           (size_t)(wid & 3) * 512 + lanebase_e;
  int stile_w = wid >> 2;
  short8 kpre[8];
#pragma unroll
  for (int kk = 0; kk < 8; kk++) kpre[kk] = *(const short8*)(kbase + kk * 32);
  for (int sc = 0; sc < TT; sc += 128) {
    f32x4 sacc[4] = {};
    __builtin_amdgcn_s_setprio(1);
#pragma unroll
    for (int kk = 0; kk < 8; kk++) {
      short8 b0 = kpre[kk];
#pragma unroll
      for (int mi = 0; mi < 4; mi++)
        sacc[mi] = __builtin_amdgcn_mfma_f32_16x16x32_bf16(afix[mi][kk], b0, sacc[mi], 0, 0, 0);
    }
    __builtin_amdgcn_s_setprio(0);
    int scn = (sc + 128 < TT) ? sc + 128 : 0;
#pragma unroll
    for (int kk = 0; kk < 8; kk++)
      kpre[kk] = *(const short8*)(kbase + (size_t)scn * CC + kk * 32);
    unsigned short* eb = ebase0 + (size_t)((sc >> 6) + stile_w) * 262144;
#pragma unroll
    for (int mi = 0; mi < 4; mi++) {
      float e0 = __expf(fminf(sacc[mi][0] * SCALE, ECLAMP));
      float e1 = __expf(fminf(sacc[mi][1] * SCALE, ECLAMP));
      float e2 = __expf(fminf(sacc[mi][2] * SCALE, ECLAMP));
      float e3 = __expf(fminf(sacc[mi][3] * SCALE, ECLAMP));
      zacc[mi][0] += e0; zacc[mi][1] += e1; zacc[mi][2] += e2; zacc[mi][3] += e3;
      uint2 pk;
      pk.x = cvtpk(e0, e1);
      pk.y = cvtpk(e2, e3);
      *(uint2*)(eb + (mi >> 1) * 2048 + (mi & 1) * 256) = pk;  // 512B coalesced/wave
    }
  }
#pragma unroll
  for (int mi = 0; mi < 4; mi++)
#pragma unroll
    for (int r = 0; r < 4; r++) {
      float z = zacc[mi][r];
      z += __shfl_xor(z, 1); z += __shfl_xor(z, 2);
      z += __shfl_xor(z, 4); z += __shfl_xor(z, 8);
      zacc[mi][r] = z;
    }
  if (l15 == 0) {
#pragma unroll
    for (int mi = 0; mi < 4; mi++)
#pragma unroll
      for (int r = 0; r < 4; r++) Zp[wid][mi * 16 + qd * 4 + r] = zacc[mi][r];
  }
  __syncthreads();
  if (tid < 64) {
    float Z = 0.0f;
#pragma unroll
    for (int w = 0; w < 8; w++) Z += Zp[w][tid];
    float zi = 1.0f / Z;
    zinv[t0 + tid] = zi;
    zfin[tid] = zi;
  }
  __syncthreads();
  // ---- fused V' epilogue (fragment layout): V'[c][t0..+64] = zinv[t]*V[c][t]
  {
    int c = tid >> 1, half = tid & 1;
    const unsigned short* vsrc = vtb + (size_t)c * TT + t0 + half * 32;
    unsigned short* vbase = vpt + (size_t)batch * 1048576u +
                            ((size_t)(c >> 4) * 128 + tile * 2 + half) * 512 +
                            (size_t)(c & 15) * 8;
#pragma unroll
    for (int j = 0; j < 4; j++) {
      short8 v = *(const short8*)(vsrc + j * 8);
      float f[8];
#pragma unroll
      for (int e = 0; e < 8; e++)
        f[e] = bf2f((unsigned short)v[e]) * zfin[half * 32 + j * 8 + e];
      union { unsigned int u[4]; short8 s; } o;
      o.u[0] = cvtpk(f[0], f[1]);
      o.u[1] = cvtpk(f[2], f[3]);
      o.u[2] = cvtpk(f[4], f[5]);
      o.u[3] = cvtpk(f[6], f[7]);
      *(short8*)(vbase + (size_t)j * 128) = o.s;
    }
  }
}

// ---------------- K4n: attnG v2 — gload_lds dbuf GEMM out = E·V' + x --------
// s-tile 32, grid 512 (2 blocks/CU, 16 waves/CU). E staged via global_load_lds
// (fragment layout == linear lane order), V' register-prefetched (L2-resident).
__global__ __launch_bounds__(512, 4) void attnG_kernel(
    const unsigned short* __restrict__ et, const unsigned short* __restrict__ vpt,
    const void* __restrict__ xv, float* __restrict__ out,
    const int* __restrict__ flagp) {
  alignas(16) __shared__ unsigned short Ebuf[2][4096];  // 2 x 8 KB
  int bx = blockIdx.x;
  int batch = (bx & 7) >> 1;
  int tile = (bx >> 3) * 2 + (bx & 1);  // s-tile32 [0,128)
  int flag = *flagp;
  int tid = threadIdx.x, wid = tid >> 6, lane = tid & 63, qd = lane >> 4, l15 = lane & 15;
  const unsigned short* etb64 =
      et + (size_t)batch * 16777216u + (size_t)(tile >> 1) * 262144;
  int mihalf = (tile & 1) * 2;
  const unsigned short* vfb = vpt + (size_t)batch * 1048576u;
  f32x4 oacc[2][2] = {};
  short8 vpre[8];

#define STAGE(BUF, TC)                                                               \
  {                                                                                  \
    const unsigned short* gsrc = etb64 +                                             \
        (size_t)(((TC) >> 5) + (wid >> 1)) * 2048 + (mihalf + (wid & 1)) * 512 +     \
        lane * 8;                                                                    \
    __builtin_amdgcn_global_load_lds(                                                \
        (const __attribute__((address_space(1))) void*)gsrc,                         \
        (__attribute__((address_space(3))) void*)&Ebuf[BUF][wid * 512], 16, 0, 0);   \
  }
#define VLOAD(TC)                                                                    \
  _Pragma("unroll") for (int kt = 0; kt < 4; kt++)                                   \
  _Pragma("unroll") for (int ni = 0; ni < 2; ni++)                                   \
      vpre[kt * 2 + ni] = *(const short8*)(vfb +                                     \
          ((size_t)(wid * 2 + ni) * 128 + ((TC) >> 5) + kt) * 512 + lane * 8);

  // prologue
  STAGE(0, 0)
  VLOAD(0)
  __syncthreads();  // drains vmcnt -> Ebuf[0] + vpre ready
  for (int it = 0; it < 32; it++) {
    int tc = it * 128, buf = it & 1;
    if (it < 31) STAGE(buf ^ 1, tc + 128)  // DMA next tile; lands during MFMA
    __builtin_amdgcn_s_setprio(1);
#pragma unroll
    for (int kt = 0; kt < 4; kt++) {
      short8 a0 = *(const short8*)&Ebuf[buf][(kt * 2 + 0) * 512 + lane * 8];
      short8 a1 = *(const short8*)&Ebuf[buf][(kt * 2 + 1) * 512 + lane * 8];
#pragma unroll
      for (int ni = 0; ni < 2; ni++) {
        short8 b = vpre[kt * 2 + ni];
        oacc[0][ni] = __builtin_amdgcn_mfma_f32_16x16x32_bf16(a0, b, oacc[0][ni], 0, 0, 0);
        oacc[1][ni] = __builtin_amdgcn_mfma_f32_16x16x32_bf16(a1, b, oacc[1][ni], 0, 0, 0);
      }
    }
    __builtin_amdgcn_s_setprio(0);
    if (it < 31) VLOAD(tc + 128)
    __syncthreads();  // drains gload_lds + vpre; protects dbuf swap
  }
#undef STAGE
#undef VLOAD
  // epilogue: out(f32) = oacc + x
  int s0 = tile * 32;
#pragma unroll
  for (int mi = 0; mi < 2; mi++)
#pragma unroll
    for (int ni = 0; ni < 2; ni++)
#pragma unroll
      for (int r = 0; r < 4; r++) {
        int s = s0 + mi * 16 + qd * 4 + r;
        int c = wid * 32 + ni * 16 + l15;
        size_t idx = ((size_t)batch * TT + s) * CC + c;
        float xr = flag ? ((const float*)xv)[idx] : bf2f(((const unsigned short*)xv)[idx]);
        out[idx] = oacc[mi][ni][r] + xr;
      }
}

// ---------------- K3: zsum v8 (fallback) ------------------------------------
__global__ __launch_bounds__(512, 2) void zsum_kernel(
    const unsigned short* __restrict__ q, const unsigned short* __restrict__ k,
    float* __restrict__ zinvp, int swiz) {
  __shared__ float Zp[8][64];
  int bx = blockIdx.x;
  int batch = swiz ? ((bx & 7) >> 1) : 0;
  int tile = swiz ? ((bx >> 3) * 2 + (bx & 1)) : bx;
  const unsigned short* qb = q + (size_t)batch * TT * CC;
  const unsigned short* kb = k + (size_t)batch * TT * CC;
  float* zinv = zinvp + (size_t)batch * TT;
  int tid = threadIdx.x, wid = tid >> 6, lane = tid & 63, qd = lane >> 4, l15 = lane & 15;
  int t0 = tile * 64;
  short8 afix[4][8];
#pragma unroll
  for (int mi = 0; mi < 4; mi++)
#pragma unroll
    for (int kk = 0; kk < 8; kk++)
      afix[mi][kk] =
          *(const short8*)(qb + (size_t)(t0 + mi * 16 + l15) * CC + kk * 32 + qd * 8);
  float zacc[4][4] = {};
  const unsigned short* kbase = kb + (size_t)(wid * 16 + l15) * CC + qd * 8;
  short8 kpre[8];
#pragma unroll
  for (int kk = 0; kk < 8; kk++) kpre[kk] = *(const short8*)(kbase + kk * 32);
  for (int sc = 0; sc < TT; sc += 128) {
    f32x4 sacc[4] = {};
    __builtin_amdgcn_s_setprio(1);
#pragma unroll
    for (int kk = 0; kk < 8; kk++) {
      short8 b0 = kpre[kk];
#pragma unroll
      for (int mi = 0; mi < 4; mi++)
        sacc[mi] = __builtin_amdgcn_mfma_f32_16x16x32_bf16(afix[mi][kk], b0, sacc[mi], 0, 0, 0);
    }
    __builtin_amdgcn_s_setprio(0);
    int scn = (sc + 128 < TT) ? sc + 128 : 0;
#pragma unroll
    for (int kk = 0; kk < 8; kk++)
      kpre[kk] = *(const short8*)(kbase + (size_t)scn * CC + kk * 32);
#pragma unroll
    for (int mi = 0; mi < 4; mi++)
#pragma unroll
      for (int r = 0; r < 4; r++)
        zacc[mi][r] += __expf(fminf(sacc[mi][r] * SCALE, ECLAMP));
  }
#pragma unroll
  for (int mi = 0; mi < 4; mi++)
#pragma unroll
    for (int r = 0; r < 4; r++) {
      float z = zacc[mi][r];
      z += __shfl_xor(z, 1); z += __shfl_xor(z, 2);
      z += __shfl_xor(z, 4); z += __shfl_xor(z, 8);
      zacc[mi][r] = z;
    }
  if (l15 == 0) {
#pragma unroll
    for (int mi = 0; mi < 4; mi++)
#pragma unroll
      for (int r = 0; r < 4; r++) Zp[wid][mi * 16 + qd * 4 + r] = zacc[mi][r];
  }
  __syncthreads();
  if (tid < 64) {
    float Z = 0.0f;
#pragma unroll
    for (int w = 0; w < 8; w++) Z += Zp[w][tid];
    zinv[t0 + tid] = 1.0f / Z;
  }
}

// ---------------- K4: attn v10 (fallback) -----------------------------------
__global__ __launch_bounds__(512, 2) void attn_kernel(
    const unsigned short* __restrict__ q, const unsigned short* __restrict__ k,
    const unsigned short* __restrict__ vt, const float* __restrict__ zinvp,
    const void* __restrict__ xv, float* __restrict__ out, int swiz, int row0,
    const int* __restrict__ flagp) {
  constexpr int LPt = 136;
  alignas(16) __shared__ unsigned short Pt[2][64 * LPt];
  int bx = blockIdx.x;
  int batch = swiz ? ((bx & 7) >> 1) : 0;
  int tile = swiz ? ((bx >> 3) * 2 + (bx & 1)) : bx;
  int flag = *flagp;
  const unsigned short* qb = q + (size_t)batch * TT * CC;
  const unsigned short* kb = k + (size_t)batch * TT * CC;
  const unsigned short* vtb = vt + (size_t)batch * TT * CC;
  const float* zinv = zinvp + (size_t)batch * TT;
  int row0e = swiz ? batch * TT : row0;
  int tid = threadIdx.x, wid = tid >> 6, lane = tid & 63, qd = lane >> 4, l15 = lane & 15;
  int s0 = tile * 64;
  short8 afix[4][8];
#pragma unroll
  for (int mi = 0; mi < 4; mi++)
#pragma unroll
    for (int kk = 0; kk < 8; kk++)
      afix[mi][kk] =
          *(const short8*)(kb + (size_t)(s0 + mi * 16 + l15) * CC + kk * 32 + qd * 8);
  f32x4 oacc[4][2] = {};
  const unsigned short* qrow = qb + (size_t)(wid * 16 + l15) * CC + qd * 8;
  const unsigned short* vrow[2];
#pragma unroll
  for (int ni = 0; ni < 2; ni++)
    vrow[ni] = vtb + (size_t)(wid * 32 + ni * 16 + l15) * TT + qd * 8;
  short8 qpre[8], vpre[8];
#pragma unroll
  for (int kk = 0; kk < 8; kk++) qpre[kk] = *(const short8*)(qrow + kk * 32);
#pragma unroll
  for (int kt = 0; kt < 4; kt++)
#pragma unroll
    for (int ni = 0; ni < 2; ni++)
      vpre[kt * 2 + ni] = *(const short8*)(vrow[ni] + kt * 32);
  int t_loc = wid * 16 + l15;
  float zpre = zinv[t_loc];
  {
    f32x4 sacc[4] = {};
    __builtin_amdgcn_s_setprio(1);
#pragma unroll
    for (int kk = 0; kk < 8; kk++) {
      short8 b0 = qpre[kk];
#pragma unroll
      for (int mi = 0; mi < 4; mi++)
        sacc[mi] = __builtin_amdgcn_mfma_f32_16x16x32_bf16(afix[mi][kk], b0, sacc[mi], 0, 0, 0);
    }
    __builtin_amdgcn_s_setprio(0);
#pragma unroll
    for (int kk = 0; kk < 8; kk++)
      qpre[kk] = *(const short8*)(qrow + (size_t)128 * CC + kk * 32);
    float zz = zpre;
    zpre = zinv[128 + t_loc];
#pragma unroll
    for (int mi = 0; mi < 4; mi++)
#pragma unroll
      for (int r = 0; r < 4; r++) {
        float p = __expf(fminf(sacc[mi][r] * SCALE, ECLAMP)) * zz;
        Pt[0][(mi * 16 + qd * 4 + r) * LPt + t_loc] = f2bf(p);
      }
  }
  __syncthreads();
  for (int it = 1; it < 32; it++) {
    int tc = it * 128;
    int tn = (tc + 128 < TT) ? tc + 128 : 0;
    int buf = it & 1;
    f32x4 sacc[4] = {};
    __builtin_amdgcn_s_setprio(1);
#pragma unroll
    for (int kk = 0; kk < 8; kk++) {
      short8 b0 = qpre[kk];
#pragma unroll
      for (int mi = 0; mi < 4; mi++)
        sacc[mi] = __builtin_amdgcn_mfma_f32_16x16x32_bf16(afix[mi][kk], b0, sacc[mi], 0, 0, 0);
    }
    __builtin_amdgcn_s_setprio(0);
#pragma unroll
    for (int kk = 0; kk < 8; kk++)
      qpre[kk] = *(const short8*)(qrow + (size_t)tn * CC + kk * 32);
    float zz = zpre;
    zpre = zinv[tn + t_loc];
#pragma unroll
    for (int mi = 0; mi < 4; mi++)
#pragma unroll
      for (int r = 0; r < 4; r++) {
        float p = __expf(fminf(sacc[mi][r] * SCALE, ECLAMP)) * zz;
        Pt[buf][(mi * 16 + qd * 4 + r) * LPt + t_loc] = f2bf(p);
      }
    __builtin_amdgcn_s_setprio(1);
#pragma unroll
    for (int kt = 0; kt < 4; kt++) {
      short8 a[4];
#pragma unroll
      for (int mi = 0; mi < 4; mi++)
        a[mi] = *(const short8*)&Pt[buf ^ 1][(mi * 16 + l15) * LPt + kt * 32 + qd * 8];
#pragma unroll
      for (int ni = 0; ni < 2; ni++) {
        short8 b = vpre[kt * 2 + ni];
#pragma unroll
        for (int mi = 0; mi < 4; mi++)
          oacc[mi][ni] =
              __builtin_amdgcn_mfma_f32_16x16x32_bf16(a[mi], b, oacc[mi][ni], 0, 0, 0);
      }
    }
    __builtin_amdgcn_s_setprio(0);
#pragma unroll
    for (int kt = 0; kt < 4; kt++)
#pragma unroll
      for (int ni = 0; ni < 2; ni++)
        vpre[kt * 2 + ni] = *(const short8*)(vrow[ni] + tc + kt * 32);
    __syncthreads();
  }
  __builtin_amdgcn_s_setprio(1);
#pragma unroll
  for (int kt = 0; kt < 4; kt++) {
    short8 a[4];
#pragma unroll
    for (int mi = 0; mi < 4; mi++)
      a[mi] = *(const short8*)&Pt[1][(mi * 16 + l15) * LPt + kt * 32 + qd * 8];
#pragma unroll
    for (int ni = 0; ni < 2; ni++) {
      short8 b = vpre[kt * 2 + ni];
#pragma unroll
      for (int mi = 0; mi < 4; mi++)
        oacc[mi][ni] =
            __builtin_amdgcn_mfma_f32_16x16x32_bf16(a[mi], b, oacc[mi][ni], 0, 0, 0);
    }
  }
  __builtin_amdgcn_s_setprio(0);
#pragma unroll
  for (int mi = 0; mi < 4; mi++)
#pragma unroll
    for (int ni = 0; ni < 2; ni++)
#pragma unroll
      for (int r = 0; r < 4; r++) {
        int s = s0 + mi * 16 + qd * 4 + r;
        int c = wid * 32 + ni * 16 + l15;
        size_t idx = ((size_t)(row0e + s)) * CC + c;
        float xr = flag ? ((const float*)xv)[idx] : bf2f(((const unsigned short*)xv)[idx]);
        out[idx] = oacc[mi][ni][r] + xr;
      }
}

extern "C" void kernel_launch(void* const* d_in, const int* in_sizes, int n_in,
                              void* d_out, int out_size, void* d_ws, size_t ws_size,
                              hipStream_t stream) {
  const void* x = d_in[0];
  const void* gamma = d_in[1];
  const void* beta = d_in[2];
  const void* Wq = d_in[3];
  const void* bq = d_in[4];
  const void* Wk = d_in[5];
  const void* bk = d_in[6];
  const void* Wv = d_in[7];
  const void* bv = d_in[8];
  float* out = (float*)d_out;  // reference output dtype: float32

  char* ws = (char*)d_ws;
  int* flag = (int*)(ws + 0);
  float2* stats = (float2*)(ws + 1024);                      // 128 KiB
  unsigned short* gmb = (unsigned short*)(ws + 132096);
  unsigned short* btb = (unsigned short*)(ws + 132608);
  unsigned short* bqb = (unsigned short*)(ws + 133120);
  unsigned short* bkb = (unsigned short*)(ws + 133632);
  unsigned short* bvb = (unsigned short*)(ws + 134144);
  unsigned short* Wqb = (unsigned short*)(ws + 135168);      // 128 KiB each
  unsigned short* Wkb = (unsigned short*)(ws + 266240);
  unsigned short* Wvb = (unsigned short*)(ws + 397312);
  float* zinv = (float*)(ws + 593920);                       // 64 KiB
  unsigned short* qb = (unsigned short*)(ws + 1048576);
  const int newfull = (ws_size >= 168820736u);               // + V'(8M) + E(128M)
  const int full = (ws_size >= 26214400u);
  size_t qkv_bytes = full ? 8388608u : 2097152u;
  unsigned short* kb = (unsigned short*)((char*)qb + qkv_bytes);
  unsigned short* vtb = (unsigned short*)((char*)kb + qkv_bytes);  // V^T [b][c][t]
  unsigned short* vpt = (unsigned short*)(ws + 26214400);          // V' fragments, 8 MiB
  unsigned short* et = (unsigned short*)(ws + 34603008);           // E fragments, 128 MiB

  detect_kernel<<<dim3(1), dim3(256), 0, stream>>>((const unsigned short*)x, flag);
  cvt_all_kernel<<<dim3(773), dim3(256), 0, stream>>>(Wq, Wk, Wv, bq, bk, bv, gamma, beta,
                                                      Wqb, Wkb, Wvb, bqb, bkb, bvb, gmb,
                                                      btb, flag);
  stats_kernel<<<dim3(BB * TT / 4), dim3(256), 0, stream>>>(x, stats, flag);

  if (newfull) {
    qkv3_kernel<<<dim3(32, 6, BB), dim3(256), 0, stream>>>(
        x, stats, gmb, btb, Wqb, Wkb, Wvb, bqb, bkb, bvb, qb, kb, vtb, 0, flag);
    zsumE_kernel<<<dim3(256), dim3(512), 0, stream>>>(qb, kb, vtb, zinv, vpt, et);
    attnG_kernel<<<dim3(512), dim3(512), 0, stream>>>(et, vpt, x, out, flag);
  } else if (full) {
    qkv3_kernel<<<dim3(32, 6, BB), dim3(256), 0, stream>>>(
        x, stats, gmb, btb, Wqb, Wkb, Wvb, bqb, bkb, bvb, qb, kb, vtb, 0, flag);
    zsum_kernel<<<dim3(256), dim3(512), 0, stream>>>(qb, kb, zinv, 1);
    attn_kernel<<<dim3(256), dim3(512), 0, stream>>>(qb, kb, vtb, zinv, x, out, 1, 0,
                                                     flag);
  } else {
    for (int b = 0; b < BB; b++) {
      int row0 = b * TT;
      qkv3_kernel<<<dim3(32, 6, 1), dim3(256), 0, stream>>>(
          x, stats, gmb, btb, Wqb, Wkb, Wvb, bqb, bkb, bvb, qb, kb, vtb, row0, flag);
      zsum_kernel<<<dim3(64), dim3(512), 0, stream>>>(qb, kb, zinv, 0);
      attn_kernel<<<dim3(64), dim3(512), 0, stream>>>(qb, kb, vtb, zinv, x, out, 0, row0,
                                                      flag);
    }
  }
}